// Round 19
// baseline (314.252 us; speedup 1.0000x reference)
//
#include <hip/hip_runtime.h>

typedef unsigned short u16;
typedef unsigned int u32;
typedef __bf16 bf16x8 __attribute__((ext_vector_type(8)));
typedef float f4_t __attribute__((ext_vector_type(4)));

#define E_DIM 1024
#define L_TOT 4097
#define B_SZ 2
#define M_ROWS 8194   // B*L
#define NWIN 31
#define HHEADS 16
#define GCHUNKS 17    // ceil(4097/256)

__device__ __forceinline__ float b2f(u16 v) {
  union { u32 u; float f; } x; x.u = ((u32)v) << 16; return x.f;
}
__device__ __forceinline__ u16 f2b(float f) {
  union { float f; u32 u; } x; x.f = f;
  u32 r = (x.u + 0x7FFFu + ((x.u >> 16) & 1u)) >> 16;
  return (u16)r;
}
__device__ __forceinline__ f4_t mfma16(bf16x8 a, bf16x8 b, f4_t c) {
  return __builtin_amdgcn_mfma_f32_16x16x32_bf16(a, b, c, 0, 0, 0);
}
__device__ __forceinline__ u32 cvtpk(float lo, float hi) {
  u32 r;
  asm volatile("v_cvt_pk_bf16_f32 %0, %1, %2" : "=v"(r) : "v"(lo), "v"(hi));
  return r;
}

// async global->LDS, 16B per lane; LDS dest = wave-uniform base + lane*16
#define GLOAD16(gp, lp)                                                              \
  __builtin_amdgcn_global_load_lds(                                                  \
      (const __attribute__((address_space(1))) u32*)(gp),                            \
      (__attribute__((address_space(3))) u32*)(lp), 16, 0, 0)

#define WAITVM(N) asm volatile("s_waitcnt vmcnt(" #N ")" ::: "memory")
#define WAITLGKM asm volatile("s_waitcnt lgkmcnt(0)" ::: "memory")
#define SCHEDB __builtin_amdgcn_sched_barrier(0)

// ---------------- fused prep: hs fp32->bf16 + weight transpose/convert ----------------
__global__ __launch_bounds__(256) void prep_kernel(const float* __restrict__ hs,
                                                   u16* __restrict__ hsb,
                                                   const float* __restrict__ w0,
                                                   const float* __restrict__ w1,
                                                   const float* __restrict__ w2,
                                                   const float* __restrict__ w3,
                                                   u16* __restrict__ wtb) {
  int bid = blockIdx.x;
  if (bid < M_ROWS) {
    int i = bid * 256 + threadIdx.x;  // float4 index
    float4 v = ((const float4*)hs)[i];
    u16 o[4] = {f2b(v.x), f2b(v.y), f2b(v.z), f2b(v.w)};
    *(uint2*)(hsb + (size_t)i * 4) = *(uint2*)o;
  } else {
    int idx2 = bid - M_ROWS;          // 0..4095
    int bz = idx2 >> 10;
    int rem = idx2 & 1023;
    int bx = rem & 31, by = rem >> 5;
    const float* src = bz == 0 ? w0 : bz == 1 ? w1 : bz == 2 ? w2 : w3;
    u16* dst = wtb + (size_t)bz * E_DIM * E_DIM;
    __shared__ float tile[32][33];
    int tx = threadIdx.x & 31, ty = threadIdx.x >> 5;
    int x = bx * 32 + tx;
    int y0 = by * 32;
    for (int j = ty; j < 32; j += 8) tile[j][tx] = src[(size_t)(y0 + j) * E_DIM + x];
    __syncthreads();
    for (int j = ty; j < 32; j += 8)
      dst[(size_t)(bx * 32 + j) * E_DIM + by * 32 + tx] = f2b(tile[tx][j]);
  }
}

// ============ gemmR (QKV): 1-wave blocks, ZERO sync, direct global->reg MFMA ========
// 64 threads = 1 wave; per-wave tile 64(M) x 128(N); acc[4][8]. No LDS in main loop,
// no barriers, no waitcnt asm: lane (g,lr) of frag i loads 16B at
// A[(m0+i*16+lr)*1024 + ks*32 + g*8] (exact MFMA fragment layout). Compiler
// software-pipelines the 12 loads/iter against 32 MFMA. Reuse via L2 with the XCD
// m-range map: xcd owns 16 m-subtiles (2MB A, L2-resident) x all 24 nt, m-fast
// (B-panel 256KB hot for 16 consecutive blocks).
// Epilogue: acc -> wave-private LDS -> coalesced uint4 stores (lgkm wait only).
__global__ __launch_bounds__(64, 4) void gemmR_qkv(const u16* __restrict__ A,
                                                   const u16* __restrict__ Wt,
                                                   const float* __restrict__ b0,
                                                   const float* __restrict__ b1,
                                                   const float* __restrict__ b2,
                                                   void* __restrict__ outBase,
                                                   int M) {
  __shared__ __align__(16) u16 epi[64 * 136];  // 17 KB

  int orig = blockIdx.x;                 // grid 3096 = 8 * 387
  int xcd = orig & 7, l = orig >> 3;
  int mt, nt;
  if (l < 384) { mt = (xcd << 4) + (l & 15); nt = l >> 4; }
  else         { mt = 128; nt = xcd * 3 + (l - 384); }
  int m0 = mt * 64, n0 = nt * 128;

  int lane = threadIdx.x;                // 0..63
  int g = lane >> 4, lr = lane & 15;

  const u16* pa[4];
  const u16* pb[8];
#pragma unroll
  for (int i = 0; i < 4; i++) {
    int r = m0 + i * 16 + lr;
    if (r >= M) r = M - 1;
    pa[i] = A + (size_t)r * 1024 + g * 8;
  }
#pragma unroll
  for (int j = 0; j < 8; j++)
    pb[j] = Wt + (size_t)(n0 + j * 16 + lr) * 1024 + g * 8;

  f4_t acc[4][8] = {};

#pragma unroll 4
  for (int ks = 0; ks < 32; ++ks) {
    bf16x8 av[4], bv[8];
#pragma unroll
    for (int i = 0; i < 4; i++) av[i] = *(const bf16x8*)(pa[i] + ks * 32);
#pragma unroll
    for (int j = 0; j < 8; j++) bv[j] = *(const bf16x8*)(pb[j] + ks * 32);
#pragma unroll
    for (int i = 0; i < 4; i++)
#pragma unroll
      for (int j = 0; j < 8; j++) acc[i][j] = mfma16(av[i], bv[j], acc[i][j]);
  }

  // ---------------- epilogue: wave-private LDS, coalesced stores ----------------
  int tsel = n0 >> 10, ncb = n0 & 1023;
  const float* bp = tsel == 0 ? b0 : (tsel == 1 ? b1 : b2);
  u16* outp = (u16*)outBase + (size_t)tsel * ((size_t)M_ROWS * E_DIM);
#pragma unroll
  for (int j = 0; j < 8; j++) {
    int ncl = j * 16 + lr;               // 0..127
    float bb = bp[ncb + ncl];
#pragma unroll
    for (int i = 0; i < 4; i++) {
#pragma unroll
      for (int r = 0; r < 4; r++)
        epi[(i * 16 + g * 4 + r) * 136 + ncl] = f2b(acc[i][j][r] + bb);
    }
  }
  WAITLGKM;                              // single wave: lgkm drain suffices
  SCHEDB;
#pragma unroll
  for (int p = 0; p < 16; p++) {
    int row = p * 4 + (lane >> 4);       // 0..63
    int chunk = lane & 15;               // 16 chunks of 8 u16 = 128 cols
    int m = m0 + row;
    if (m < M) {
      *(uint4*)(outp + (size_t)m * E_DIM + ncb + chunk * 8) =
          *(const uint4*)(epi + row * 136 + chunk * 8);
    }
  }
}

// ============ gemmC_out (r13-exact, out-projection) ============
__global__ __launch_bounds__(256, 4) void gemmC_out(const u16* __restrict__ A,
                                                    const u16* __restrict__ Wt,
                                                    const float* __restrict__ b0,
                                                    void* __restrict__ outBase,
                                                    int M) {
  __shared__ __align__(16) char smraw[34816];
  u16* sA = (u16*)smraw;
  u16* sB = sA + 2 * 4096;
  float* epi32 = (float*)smraw;

  int orig = blockIdx.x;
  int xcd = orig & 7, l = orig >> 3;
  int mt, nt;
  if (l < 64)  { mt = (xcd << 3) + (l & 7); nt = l >> 3; }
  else         { mt = 64; nt = xcd; }
  int m0 = mt * 128, n0 = nt * 128;

  int t = threadIdx.x, lane = t & 63, w = t >> 6;
  int wr = w >> 1, wc = w & 1;
  int lr = lane & 15, g = lane >> 4;

  int ssrc = (((t & 3) ^ ((t >> 3) & 3)) << 3);
  const u16* pa[2];
  const u16* pb[2];
#pragma unroll
  for (int c = 0; c < 2; c++) {
    int ra = m0 + c * 64 + (t >> 2);
    if (ra >= M) ra = M - 1;
    pa[c] = A + (size_t)ra * 1024 + ssrc;
    pb[c] = Wt + (size_t)(n0 + c * 64 + (t >> 2)) * 1024 + ssrc;
  }
  int wb = w * 512;

#define STAGE(bf, ks)                                              \
  {                                                                \
    GLOAD16(pa[0] + (ks) * 32, sA + (bf) * 4096 + wb);             \
    GLOAD16(pa[1] + (ks) * 32, sA + (bf) * 4096 + 2048 + wb);      \
    GLOAD16(pb[0] + (ks) * 32, sB + (bf) * 4096 + wb);             \
    GLOAD16(pb[1] + (ks) * 32, sB + (bf) * 4096 + 2048 + wb);      \
  }

  int swz = ((g ^ ((lr >> 1) & 3)) << 3);
  int arow0 = wr * 64 + lr;
  int brow0 = wc * 64 + lr;

  f4_t acc[4][4] = {};

  STAGE(0, 0);
  STAGE(1, 1);
  WAITVM(4);
  __builtin_amdgcn_s_barrier();
  SCHEDB;

#pragma unroll 2
  for (int ks = 0; ks < 32; ++ks) {
    int bf = ks & 1;
    int base = bf * 4096;
    bf16x8 av[4], bv[4];
#pragma unroll
    for (int i = 0; i < 4; i++)
      av[i] = *(const bf16x8*)&sA[base + (arow0 + i * 16) * 32 + swz];
#pragma unroll
    for (int j = 0; j < 4; j++)
      bv[j] = *(const bf16x8*)&sB[base + (brow0 + j * 16) * 32 + swz];
    WAITLGKM;
    SCHEDB;
    __builtin_amdgcn_s_barrier();
    SCHEDB;
    if (ks < 30) STAGE(bf, ks + 2);
    SCHEDB;
    __builtin_amdgcn_s_setprio(1);
#pragma unroll
    for (int i = 0; i < 4; i++)
#pragma unroll
      for (int j = 0; j < 4; j++) acc[i][j] = mfma16(av[i], bv[j], acc[i][j]);
    __builtin_amdgcn_s_setprio(0);
    if (ks < 30) {
      WAITVM(4);
    } else if (ks == 30) {
      WAITVM(0);
    }
    if (ks < 31) {
      __builtin_amdgcn_s_barrier();
      SCHEDB;
    }
  }
  __syncthreads();

#pragma unroll
  for (int p = 0; p < 2; p++) {
    if (p) __syncthreads();
    if (wc == p) {
#pragma unroll
      for (int j = 0; j < 4; j++) {
        int ncl = j * 16 + lr;
        float bb = b0[n0 + p * 64 + ncl];
#pragma unroll
        for (int i = 0; i < 4; i++) {
          int mlb = wr * 64 + i * 16 + g * 4;
#pragma unroll
          for (int r = 0; r < 4; r++) epi32[(mlb + r) * 68 + ncl] = acc[i][j][r] + bb;
        }
      }
    }
    __syncthreads();
    int row = t >> 1, qr = t & 1;
    int m = m0 + row;
    if (m < M) {
      float* op = (float*)outBase + (size_t)m * E_DIM + n0 + p * 64 + qr * 32;
      const float* lp = epi32 + row * 68 + qr * 32;
#pragma unroll
      for (int qd = 0; qd < 8; qd++) ((float4*)op)[qd] = ((const float4*)lp)[qd];
    }
  }
#undef STAGE
}

// ========== fused attention: gattn1 (blocks 0..543) + wattn v2 (blocks 544..1535) ====
#define VT_IDX(d, k) ((d) * 264 + ((k) ^ ((((d) >> 3) & 7) << 3)))
__global__ __launch_bounds__(256) void attn_fused(const u16* __restrict__ Qb,
                                                  const u16* __restrict__ Kb,
                                                  const u16* __restrict__ Vb,
                                                  float* __restrict__ part,
                                                  u16* __restrict__ winctx) {
  __shared__ __align__(16) char smem[66560];
  int bid = blockIdx.x;
  int t = threadIdx.x;

  if (bid < 544) {
    int c = bid % GCHUNKS;
    int rem = bid / GCHUNKS;
    int h = rem & 15, b = rem >> 4;
    float* qsh = (float*)smem;
    float* red = qsh + 64;
    float* psh = red + 4;
    float* cred = psh + 256;

    size_t base = (size_t)b * L_TOT * E_DIM + h * 64;
    if (t < 64) qsh[t] = b2f(Qb[base + t]);
    __syncthreads();

    int row = c * 256 + t;
    bool valid = row < L_TOT;
    float dot = -1e30f;
    if (valid) {
      const u16* kp = Kb + base + (size_t)row * E_DIM;
      float acc = 0.f;
#pragma unroll
      for (int j = 0; j < 64; j += 8) {
        uint4 kv = *(const uint4*)(kp + j);
        const u16* kk = (const u16*)&kv;
#pragma unroll
        for (int q = 0; q < 8; q++) acc += qsh[j + q] * b2f(kk[q]);
      }
      dot = acc * 0.125f;
    }
    float m = dot;
    for (int mask = 1; mask < 64; mask <<= 1) m = fmaxf(m, __shfl_xor(m, mask));
    if ((t & 63) == 0) red[t >> 6] = m;
    __syncthreads();
    m = fmaxf(fmaxf(red[0], red[1]), fmaxf(red[2], red[3]));
    float p = valid ? __expf(dot - m) : 0.f;
    psh[t] = p;
    float s = p;
    for (int mask = 1; mask < 64; mask <<= 1) s += __shfl_xor(s, mask);
    __syncthreads();
    if ((t & 63) == 0) red[t >> 6] = s;
    __syncthreads();
    s = red[0] + red[1] + red[2] + red[3];

    int d = t & 63, gq = t >> 6;
    float acc = 0.f;
#pragma unroll 4
    for (int i = 0; i < 64; i++) {
      int sl = gq * 64 + i;
      int r2 = c * 256 + sl;
      if (r2 < L_TOT) acc += psh[sl] * b2f(Vb[base + (size_t)r2 * E_DIM + d]);
    }
    cred[gq * 64 + d] = acc;
    __syncthreads();
    if (t < 64) {
      float v = cred[t] + cred[64 + t] + cred[128 + t] + cred[192 + t];
      float* pp = part + (((size_t)(b * HHEADS + h) * GCHUNKS + c) * 66);
      pp[t] = v;
      if (t == 0) { pp[64] = m; pp[65] = s; }
    }
    return;
  }

  int id = bid - 544;
  int wdw = id % NWIN;
  int rem = id / NWIN;
  int h = rem & 15, b = rem >> 4;

  u16* Ks = (u16*)smem;
  u16* Vt = Ks + 256 * 64;

  int lane = t & 63, wv = t >> 6;
  int g = lane >> 4, lr = lane & 15;
  size_t rowbase = (size_t)b * L_TOT + 1 + (size_t)wdw * 128;
  int hoff = h * 64;

  {
    int rsub = t >> 3;
    int ssrc = ((t & 7) ^ (rsub & 7)) * 8;
    const u16* kp = Kb + (rowbase + rsub) * E_DIM + hoff + ssrc;
#pragma unroll
    for (int c = 0; c < 8; c++)
      GLOAD16(kp + (size_t)c * 32 * E_DIM, Ks + c * 2048 + wv * 512);
  }
#pragma unroll
  for (int rep = 0; rep < 8; rep++) {
    int u = rep * 256 + t;
    int i = u >> 3;
    int d0 = (u & 7) * 8;
    uint4 v = *(const uint4*)(Vb + (rowbase + i) * E_DIM + hoff + d0);
    const u16* pv = (const u16*)&v;
#pragma unroll
    for (int j = 0; j < 8; j++) Vt[VT_IDX(d0 + j, i)] = pv[j];
  }
  __syncthreads();

  int slo = (2 * (g & 1)) * 16 + lr;
  int shi = slo + 16;

  for (int grp = 0; grp < 4; grp++) {
    int q0 = grp * 64 + wv * 16;
    const u16* qp = Qb + (rowbase + q0 + lr) * E_DIM + hoff;
    bf16x8 qa0 = *(const bf16x8*)(qp + g * 8);
    bf16x8 qa1 = *(const bf16x8*)(qp + 32 + g * 8);

    f4_t s[16];
    __builtin_amdgcn_s_setprio(1);
#pragma unroll
    for (int ki = 0; ki < 16; ki++) {
      int row = ki * 16 + lr;
      bf16x8 ka0 = *(const bf16x8*)&Ks[row * 64 + ((g ^ (lr & 7)) << 3)];
      bf16x8 ka1 = *(const bf16x8*)&Ks[row * 64 + (((4 + g) ^ (lr & 7)) << 3)];
      f4_t z = {};
      z = mfma16(ka0, qa0, z);
      z = mfma16(ka1, qa1, z);
      s[ki] = z;
    }
    __builtin_amdgcn_s_setprio(0);

    float mx = -1e30f;
#pragma unroll
    for (int ki = 0; ki < 16; ki++) {
      mx = fmaxf(mx, fmaxf(fmaxf(s[ki][0], s[ki][1]), fmaxf(s[ki][2], s[ki][3])));
    }
    mx = fmaxf(mx, __shfl_xor(mx, 16));
    mx = fmaxf(mx, __shfl_xor(mx, 32));
    float mx8 = mx * 0.125f;
    float sum = 0.f;
    u32 pk[16][2];
#pragma unroll
    for (int ki = 0; ki < 16; ki++) {
      float p0 = __expf(fmaf(s[ki][0], 0.125f, -mx8));
      float p1 = __expf(fmaf(s[ki][1], 0.125f, -mx8));
      float p2 = __expf(fmaf(s[ki][2], 0.125f, -mx8));
      float p3 = __expf(fmaf(s[ki][3], 0.125f, -mx8));
      sum += (p0 + p1) + (p2 + p3);
      pk[ki][0] = cvtpk(p0, p1);
      pk[ki][1] = cvtpk(p2, p3);
    }
    sum += __shfl_xor(sum, 16);
    sum += __shfl_xor(sum, 32);
    float inv = 1.0f / sum;

    u32 paw[8][4];
    bool hi = g >= 2;
#pragma unroll
    for (int kt = 0; kt < 8; kt++) {
      u32 v00 = __shfl((int)pk[kt * 2][0], slo);
      u32 v01 = __shfl((int)pk[kt * 2][1], slo);
      u32 v10 = __shfl((int)pk[kt * 2 + 1][0], slo);
      u32 v11 = __shfl((int)pk[kt * 2 + 1][1], slo);
      u32 w00 = __shfl((int)pk[kt * 2][0], shi);
      u32 w01 = __shfl((int)pk[kt * 2][1], shi);
      u32 w10 = __shfl((int)pk[kt * 2 + 1][0], shi);
      u32 w11 = __shfl((int)pk[kt * 2 + 1][1], shi);
      paw[kt][0] = hi ? v10 : v00;
      paw[kt][1] = hi ? v11 : v01;
      paw[kt][2] = hi ? w10 : w00;
      paw[kt][3] = hi ? w11 : w01;
    }

    f4_t o[4] = {};
    __builtin_amdgcn_s_setprio(1);
#pragma unroll
    for (int dtile = 0; dtile < 4; dtile++) {
      int d = dtile * 16 + lr;
      int dswz = (((d >> 3) & 7) << 3);
#pragma unroll
      for (int kt = 0; kt < 8; kt++) {
        int kphys = (kt * 32 + g * 8) ^ dswz;
        bf16x8 vb = *(const bf16x8*)&Vt[d * 264 + kphys];
        o[dtile] = mfma16(*(const bf16x8*)&paw[kt][0], vb, o[dtile]);
      }
    }
    __builtin_amdgcn_s_setprio(0);

    float invr[4];
#pragma unroll
    for (int r = 0; r < 4; r++) invr[r] = __shfl(inv, g * 4 + r);
    size_t orow = (size_t)(b * NWIN + wdw) * 256 + q0;
#pragma unroll
    for (int dtile = 0; dtile < 4; dtile++) {
#pragma unroll
      for (int r = 0; r < 4; r++) {
        winctx[(orow + g * 4 + r) * E_DIM + hoff + dtile * 16 + lr] =
            f2b(o[dtile][r] * invr[r]);
      }
    }
  }
}

// ------- combine2: overlap-average (blocks 0..4095) + gattn2 (block 4096) -------
__global__ __launch_bounds__(256) void combine2_kernel(const u16* __restrict__ winctx,
                                                       const float* __restrict__ part,
                                                       u16* __restrict__ ctxb) {
  if (blockIdx.x == 4096) {
    for (int i = threadIdx.x; i < 2048; i += 256) {
      int bh = i >> 6, d = i & 63;
      int b = bh >> 4, h = bh & 15;
      const float* pp = part + ((size_t)(b * HHEADS + h) * GCHUNKS) * 66;
      float m = -1e30f;
#pragma unroll
      for (int c = 0; c < GCHUNKS; c++) m = fmaxf(m, pp[c * 66 + 64]);
      float stot = 0.f, acc = 0.f;
#pragma unroll
      for (int c = 0; c < GCHUNKS; c++) {
        float w = __expf(pp[c * 66 + 64] - m);
        stot += pp[c * 66 + 65] * w;
        acc += pp[c * 66 + d] * w;
      }
      ctxb[(size_t)b * L_TOT * E_DIM + h * 64 + d] = f2b(acc / stot);
    }
    return;
  }
  int idx = blockIdx.x * 256 + threadIdx.x;
  int e0 = (idx & 127) * 8;
  int p = (idx >> 7) & 4095;
  int b = idx >> 19;
  int whi = p >> 7;
  if (whi > 30) whi = 30;
  int off_hi = p - whi * 128;
  int wlo = whi - 1;
  bool has_lo = (wlo >= 0) && (off_hi < 128);

  uint4 vhi = *(const uint4*)(winctx + (((size_t)(b * NWIN + whi) * 256 + off_hi) * E_DIM) + e0);
  const u16* ph = (const u16*)&vhi;
  float vals[8];
#pragma unroll
  for (int j = 0; j < 8; j++) vals[j] = b2f(ph[j]);
  if (has_lo) {
    uint4 vlo = *(const uint4*)(winctx + (((size_t)(b * NWIN + wlo) * 256 + off_hi + 128) * E_DIM) + e0);
    const u16* pl = (const u16*)&vlo;
#pragma unroll
    for (int j = 0; j < 8; j++) vals[j] = (vals[j] + b2f(pl[j])) * 0.5f;
  }
  u16 out[8];
#pragma unroll
  for (int j = 0; j < 8; j++) out[j] = f2b(vals[j]);
  *(uint4*)(ctxb + ((size_t)b * L_TOT + 1 + p) * E_DIM + e0) = *(uint4*)out;
}

// ---------------- launch ----------------
extern "C" void kernel_launch(void* const* d_in, const int* in_sizes, int n_in,
                              void* d_out, int out_size, void* d_ws, size_t ws_size,
                              hipStream_t stream) {
  const float* hs = (const float*)d_in[0];
  const float* Wq = (const float*)d_in[1];
  const float* bq = (const float*)d_in[2];
  const float* Wk = (const float*)d_in[3];
  const float* bk = (const float*)d_in[4];
  const float* Wv = (const float*)d_in[5];
  const float* bv = (const float*)d_in[6];
  const float* Wo = (const float*)d_in[7];
  const float* bo = (const float*)d_in[8];

  const size_t BLE = (size_t)M_ROWS * E_DIM;
  const size_t BLE_B = BLE * 2;
  const size_t EE = (size_t)E_DIM * E_DIM;

  char* ws = (char*)d_ws;
  u16* hsb = (u16*)(ws);
  u16* wtb = (u16*)(ws + BLE_B);
  u16* qkv = (u16*)(ws + BLE_B + 4 * EE * 2);
  u16* Qb = qkv;
  u16* Kb = qkv + BLE;
  u16* Vb = qkv + 2 * BLE;
  u16* ctxb = (u16*)(ws + BLE_B + 4 * EE * 2 + 3 * BLE_B);
  u16* winctx = (u16*)(ws + BLE_B + 4 * EE * 2 + 4 * BLE_B);
  float* gpart = (float*)(ws + BLE_B + 4 * EE * 2 + 4 * BLE_B +
                          (size_t)B_SZ * NWIN * 256 * E_DIM * 2);

  // fused hs convert + weight transpose
  prep_kernel<<<M_ROWS + 4096, 256, 0, stream>>>(hs, hsb, Wq, Wk, Wv, Wo, wtb);
  // QKV fused: 129 m-tiles(64) x 24 n-tiles(128) = 3096 one-wave blocks, zero sync
  gemmR_qkv<<<3096, 64, 0, stream>>>(hsb, wtb, bq, bk, bv, qkv, M_ROWS);
  // fused gattn1 (544) + wattn (992) = 1536 blocks
  attn_fused<<<1536, 256, 0, stream>>>(Qb, Kb, Vb, gpart, winctx);
  combine2_kernel<<<4097, 256, 0, stream>>>(winctx, gpart, ctxb);
  // output projection: 65 m-tiles x 8 n-tiles (BN=128) = 520 blocks
  gemmC_out<<<520, 256, 0, stream>>>(ctxb, wtb + 3 * EE, bo, d_out, M_ROWS);
}

// Round 20
// 203.615 us; speedup vs baseline: 1.5434x; 1.5434x over previous
//
#include <hip/hip_runtime.h>

typedef unsigned short u16;
typedef unsigned int u32;
typedef __bf16 bf16x8 __attribute__((ext_vector_type(8)));
typedef float f4_t __attribute__((ext_vector_type(4)));

#define E_DIM 1024
#define L_TOT 4097
#define B_SZ 2
#define M_ROWS 8194   // B*L
#define NWIN 31
#define HHEADS 16
#define GCHUNKS 17    // ceil(4097/256)

__device__ __forceinline__ float b2f(u16 v) {
  union { u32 u; float f; } x; x.u = ((u32)v) << 16; return x.f;
}
__device__ __forceinline__ u16 f2b(float f) {
  union { float f; u32 u; } x; x.f = f;
  u32 r = (x.u + 0x7FFFu + ((x.u >> 16) & 1u)) >> 16;
  return (u16)r;
}
__device__ __forceinline__ f4_t mfma16(bf16x8 a, bf16x8 b, f4_t c) {
  return __builtin_amdgcn_mfma_f32_16x16x32_bf16(a, b, c, 0, 0, 0);
}
__device__ __forceinline__ u32 cvtpk(float lo, float hi) {
  u32 r;
  asm volatile("v_cvt_pk_bf16_f32 %0, %1, %2" : "=v"(r) : "v"(lo), "v"(hi));
  return r;
}

// async global->LDS, 16B per lane; LDS dest = wave-uniform base + lane*16
#define GLOAD16(gp, lp)                                                              \
  __builtin_amdgcn_global_load_lds(                                                  \
      (const __attribute__((address_space(1))) u32*)(gp),                            \
      (__attribute__((address_space(3))) u32*)(lp), 16, 0, 0)

#define WAITVM(N) asm volatile("s_waitcnt vmcnt(" #N ")" ::: "memory")
#define WAITLGKM asm volatile("s_waitcnt lgkmcnt(0)" ::: "memory")
#define SCHEDB __builtin_amdgcn_sched_barrier(0)

// ---------------- fused prep: hs fp32->bf16 + weight transpose/convert ----------------
__global__ __launch_bounds__(256) void prep_kernel(const float* __restrict__ hs,
                                                   u16* __restrict__ hsb,
                                                   const float* __restrict__ w0,
                                                   const float* __restrict__ w1,
                                                   const float* __restrict__ w2,
                                                   const float* __restrict__ w3,
                                                   u16* __restrict__ wtb) {
  int bid = blockIdx.x;
  if (bid < M_ROWS) {
    int i = bid * 256 + threadIdx.x;  // float4 index
    float4 v = ((const float4*)hs)[i];
    u16 o[4] = {f2b(v.x), f2b(v.y), f2b(v.z), f2b(v.w)};
    *(uint2*)(hsb + (size_t)i * 4) = *(uint2*)o;
  } else {
    int idx2 = bid - M_ROWS;          // 0..4095
    int bz = idx2 >> 10;
    int rem = idx2 & 1023;
    int bx = rem & 31, by = rem >> 5;
    const float* src = bz == 0 ? w0 : bz == 1 ? w1 : bz == 2 ? w2 : w3;
    u16* dst = wtb + (size_t)bz * E_DIM * E_DIM;
    __shared__ float tile[32][33];
    int tx = threadIdx.x & 31, ty = threadIdx.x >> 5;
    int x = bx * 32 + tx;
    int y0 = by * 32;
    for (int j = ty; j < 32; j += 8) tile[j][tx] = src[(size_t)(y0 + j) * E_DIM + x];
    __syncthreads();
    for (int j = ty; j < 32; j += 8)
      dst[(size_t)(bx * 32 + j) * E_DIM + by * 32 + tx] = f2b(tile[tx][j]);
  }
}

// ============ gemmF (QKV): BM=128 x BN=256 wide tile, BK=32, dbuf, counted vmcnt ====
__global__ __launch_bounds__(256, 2) void gemmF_qkv(const u16* __restrict__ A,
                                                    const u16* __restrict__ Wt,
                                                    const float* __restrict__ b0,
                                                    const float* __restrict__ b1,
                                                    const float* __restrict__ b2,
                                                    void* __restrict__ outBase,
                                                    int M) {
  __shared__ __align__(16) char smraw[49152];  // A 16KB + B 32KB; epi 34.8KB alias
  u16* sA = (u16*)smraw;            // [2][128][32] u16
  u16* sB = sA + 2 * 4096;          // [2][256][32] u16
  u16* epi16 = (u16*)smraw;         // [128][136] u16

  // XCD m-range mapping: xcd owns m-tiles [8x,8x+8) x all 12 nt, m-fast.
  int orig = blockIdx.x;
  int xcd = orig & 7, l = orig >> 3;
  int mt, nt;
  if (l < 96)      { mt = (xcd << 3) + (l & 7); nt = l >> 3; }
  else if (l == 96){ mt = 64; nt = xcd; }
  else             { if (xcd >= 4) return; mt = 64; nt = 8 + xcd; }
  int m0 = mt * 128, n0 = nt * 256;

  int t = threadIdx.x, lane = t & 63, w = t >> 6;
  int wr = w >> 1, wc = w & 1;
  int lr = lane & 15, g = lane >> 4;

  int ssrc = (((t & 3) ^ ((t >> 3) & 3)) << 3);
  const u16* pa[2];
  const u16* pb[4];
#pragma unroll
  for (int c = 0; c < 2; c++) {
    int ra = m0 + c * 64 + (t >> 2);
    if (ra >= M) ra = M - 1;
    pa[c] = A + (size_t)ra * 1024 + ssrc;
  }
#pragma unroll
  for (int c = 0; c < 4; c++)
    pb[c] = Wt + (size_t)(n0 + c * 64 + (t >> 2)) * 1024 + ssrc;
  int wb = w * 512;

#define STAGE(bf, ks)                                              \
  {                                                                \
    GLOAD16(pa[0] + (ks) * 32, sA + (bf) * 4096 + wb);             \
    GLOAD16(pa[1] + (ks) * 32, sA + (bf) * 4096 + 2048 + wb);      \
    GLOAD16(pb[0] + (ks) * 32, sB + (bf) * 8192 + wb);             \
    GLOAD16(pb[1] + (ks) * 32, sB + (bf) * 8192 + 2048 + wb);      \
    GLOAD16(pb[2] + (ks) * 32, sB + (bf) * 8192 + 4096 + wb);      \
    GLOAD16(pb[3] + (ks) * 32, sB + (bf) * 8192 + 6144 + wb);      \
  }

  int swz = ((g ^ ((lr >> 1) & 3)) << 3);
  int arow0 = wr * 64 + lr;
  int brow0 = wc * 128 + lr;

  f4_t acc[4][8] = {};

  // prologue: K-steps 0,1 in flight (12 DMA)
  STAGE(0, 0);
  STAGE(1, 1);
  WAITVM(6);                        // retires STAGE(0)'s 6 (oldest)
  __builtin_amdgcn_s_barrier();
  SCHEDB;

#pragma unroll 2
  for (int ks = 0; ks < 32; ++ks) {
    int bf = ks & 1;
    int baseA = bf * 4096, baseB = bf * 8192;
    bf16x8 av[4], bv[8];
#pragma unroll
    for (int i = 0; i < 4; i++)
      av[i] = *(const bf16x8*)&sA[baseA + (arow0 + i * 16) * 32 + swz];
#pragma unroll
    for (int j = 0; j < 8; j++)
      bv[j] = *(const bf16x8*)&sB[baseB + (brow0 + j * 16) * 32 + swz];
    // mid barrier: reads done blockwide; DMA prefetch stays in flight
    WAITLGKM;
    SCHEDB;
    __builtin_amdgcn_s_barrier();
    SCHEDB;
    if (ks < 30) STAGE(bf, ks + 2);
    SCHEDB;
    __builtin_amdgcn_s_setprio(1);
#pragma unroll
    for (int i = 0; i < 4; i++)
#pragma unroll
      for (int j = 0; j < 8; j++) acc[i][j] = mfma16(av[i], bv[j], acc[i][j]);
    __builtin_amdgcn_s_setprio(0);
    if (ks < 30) {
      WAITVM(6);                    // retires STAGE(ks+1); STAGE(ks+2) stays in flight
    } else if (ks == 30) {
      WAITVM(0);
    }
    if (ks < 31) {
      __builtin_amdgcn_s_barrier();
      SCHEDB;
    }
  }
  __syncthreads();  // protect LDS before epilogue aliasing

  // ---------------- epilogue: 2 passes of 128 cols via LDS ----------------
  int tsel = n0 >> 10, ncb = n0 & 1023;
  const float* bp = tsel == 0 ? b0 : (tsel == 1 ? b1 : b2);
  u16* outp = (u16*)outBase + (size_t)tsel * ((size_t)M_ROWS * E_DIM);
#pragma unroll
  for (int p = 0; p < 2; p++) {
    if (p) __syncthreads();
    if (wc == p) {
#pragma unroll
      for (int j = 0; j < 8; j++) {
        int ncl = j * 16 + lr;                 // 0..127
        float bb = bp[ncb + p * 128 + ncl];
#pragma unroll
        for (int i = 0; i < 4; i++) {
          int mlb = wr * 64 + i * 16 + g * 4;
#pragma unroll
          for (int r = 0; r < 4; r++) epi16[(mlb + r) * 136 + ncl] = f2b(acc[i][j][r] + bb);
        }
      }
    }
    __syncthreads();
    int row = t >> 1, half = t & 1;
    int m = m0 + row;
    if (m < M) {
      u16* op = outp + (size_t)m * E_DIM + ncb + p * 128 + half * 64;
      const u16* lp = epi16 + row * 136 + half * 64;
#pragma unroll
      for (int qd = 0; qd < 8; qd++) ((uint4*)op)[qd] = ((const uint4*)lp)[qd];
    }
  }
#undef STAGE
}

// ============ gemmC_out (r13-exact, out-projection) ============
__global__ __launch_bounds__(256, 4) void gemmC_out(const u16* __restrict__ A,
                                                    const u16* __restrict__ Wt,
                                                    const float* __restrict__ b0,
                                                    void* __restrict__ outBase,
                                                    int M) {
  __shared__ __align__(16) char smraw[34816];
  u16* sA = (u16*)smraw;
  u16* sB = sA + 2 * 4096;
  float* epi32 = (float*)smraw;

  int orig = blockIdx.x;
  int xcd = orig & 7, l = orig >> 3;
  int mt, nt;
  if (l < 64)  { mt = (xcd << 3) + (l & 7); nt = l >> 3; }
  else         { mt = 64; nt = xcd; }
  int m0 = mt * 128, n0 = nt * 128;

  int t = threadIdx.x, lane = t & 63, w = t >> 6;
  int wr = w >> 1, wc = w & 1;
  int lr = lane & 15, g = lane >> 4;

  int ssrc = (((t & 3) ^ ((t >> 3) & 3)) << 3);
  const u16* pa[2];
  const u16* pb[2];
#pragma unroll
  for (int c = 0; c < 2; c++) {
    int ra = m0 + c * 64 + (t >> 2);
    if (ra >= M) ra = M - 1;
    pa[c] = A + (size_t)ra * 1024 + ssrc;
    pb[c] = Wt + (size_t)(n0 + c * 64 + (t >> 2)) * 1024 + ssrc;
  }
  int wb = w * 512;

#define STAGE(bf, ks)                                              \
  {                                                                \
    GLOAD16(pa[0] + (ks) * 32, sA + (bf) * 4096 + wb);             \
    GLOAD16(pa[1] + (ks) * 32, sA + (bf) * 4096 + 2048 + wb);      \
    GLOAD16(pb[0] + (ks) * 32, sB + (bf) * 4096 + wb);             \
    GLOAD16(pb[1] + (ks) * 32, sB + (bf) * 4096 + 2048 + wb);      \
  }

  int swz = ((g ^ ((lr >> 1) & 3)) << 3);
  int arow0 = wr * 64 + lr;
  int brow0 = wc * 64 + lr;

  f4_t acc[4][4] = {};

  STAGE(0, 0);
  STAGE(1, 1);
  WAITVM(4);
  __builtin_amdgcn_s_barrier();
  SCHEDB;

#pragma unroll 2
  for (int ks = 0; ks < 32; ++ks) {
    int bf = ks & 1;
    int base = bf * 4096;
    bf16x8 av[4], bv[4];
#pragma unroll
    for (int i = 0; i < 4; i++)
      av[i] = *(const bf16x8*)&sA[base + (arow0 + i * 16) * 32 + swz];
#pragma unroll
    for (int j = 0; j < 4; j++)
      bv[j] = *(const bf16x8*)&sB[base + (brow0 + j * 16) * 32 + swz];
    WAITLGKM;
    SCHEDB;
    __builtin_amdgcn_s_barrier();
    SCHEDB;
    if (ks < 30) STAGE(bf, ks + 2);
    SCHEDB;
    __builtin_amdgcn_s_setprio(1);
#pragma unroll
    for (int i = 0; i < 4; i++)
#pragma unroll
      for (int j = 0; j < 4; j++) acc[i][j] = mfma16(av[i], bv[j], acc[i][j]);
    __builtin_amdgcn_s_setprio(0);
    if (ks < 30) {
      WAITVM(4);
    } else if (ks == 30) {
      WAITVM(0);
    }
    if (ks < 31) {
      __builtin_amdgcn_s_barrier();
      SCHEDB;
    }
  }
  __syncthreads();

#pragma unroll
  for (int p = 0; p < 2; p++) {
    if (p) __syncthreads();
    if (wc == p) {
#pragma unroll
      for (int j = 0; j < 4; j++) {
        int ncl = j * 16 + lr;
        float bb = b0[n0 + p * 64 + ncl];
#pragma unroll
        for (int i = 0; i < 4; i++) {
          int mlb = wr * 64 + i * 16 + g * 4;
#pragma unroll
          for (int r = 0; r < 4; r++) epi32[(mlb + r) * 68 + ncl] = acc[i][j][r] + bb;
        }
      }
    }
    __syncthreads();
    int row = t >> 1, qr = t & 1;
    int m = m0 + row;
    if (m < M) {
      float* op = (float*)outBase + (size_t)m * E_DIM + n0 + p * 64 + qr * 32;
      const float* lp = epi32 + row * 68 + qr * 32;
#pragma unroll
      for (int qd = 0; qd < 8; qd++) ((float4*)op)[qd] = ((const float4*)lp)[qd];
    }
  }
#undef STAGE
}

// ========== fused attention: gattn1 (blocks 0..543) + wattn v2 (blocks 544..1535) ====
#define VT_IDX(d, k) ((d) * 264 + ((k) ^ ((((d) >> 3) & 7) << 3)))
__global__ __launch_bounds__(256) void attn_fused(const u16* __restrict__ Qb,
                                                  const u16* __restrict__ Kb,
                                                  const u16* __restrict__ Vb,
                                                  float* __restrict__ part,
                                                  u16* __restrict__ winctx) {
  __shared__ __align__(16) char smem[66560];
  int bid = blockIdx.x;
  int t = threadIdx.x;

  if (bid < 544) {
    int c = bid % GCHUNKS;
    int rem = bid / GCHUNKS;
    int h = rem & 15, b = rem >> 4;
    float* qsh = (float*)smem;
    float* red = qsh + 64;
    float* psh = red + 4;
    float* cred = psh + 256;

    size_t base = (size_t)b * L_TOT * E_DIM + h * 64;
    if (t < 64) qsh[t] = b2f(Qb[base + t]);
    __syncthreads();

    int row = c * 256 + t;
    bool valid = row < L_TOT;
    float dot = -1e30f;
    if (valid) {
      const u16* kp = Kb + base + (size_t)row * E_DIM;
      float acc = 0.f;
#pragma unroll
      for (int j = 0; j < 64; j += 8) {
        uint4 kv = *(const uint4*)(kp + j);
        const u16* kk = (const u16*)&kv;
#pragma unroll
        for (int q = 0; q < 8; q++) acc += qsh[j + q] * b2f(kk[q]);
      }
      dot = acc * 0.125f;
    }
    float m = dot;
    for (int mask = 1; mask < 64; mask <<= 1) m = fmaxf(m, __shfl_xor(m, mask));
    if ((t & 63) == 0) red[t >> 6] = m;
    __syncthreads();
    m = fmaxf(fmaxf(red[0], red[1]), fmaxf(red[2], red[3]));
    float p = valid ? __expf(dot - m) : 0.f;
    psh[t] = p;
    float s = p;
    for (int mask = 1; mask < 64; mask <<= 1) s += __shfl_xor(s, mask);
    __syncthreads();
    if ((t & 63) == 0) red[t >> 6] = s;
    __syncthreads();
    s = red[0] + red[1] + red[2] + red[3];

    int d = t & 63, gq = t >> 6;
    float acc = 0.f;
#pragma unroll 4
    for (int i = 0; i < 64; i++) {
      int sl = gq * 64 + i;
      int r2 = c * 256 + sl;
      if (r2 < L_TOT) acc += psh[sl] * b2f(Vb[base + (size_t)r2 * E_DIM + d]);
    }
    cred[gq * 64 + d] = acc;
    __syncthreads();
    if (t < 64) {
      float v = cred[t] + cred[64 + t] + cred[128 + t] + cred[192 + t];
      float* pp = part + (((size_t)(b * HHEADS + h) * GCHUNKS + c) * 66);
      pp[t] = v;
      if (t == 0) { pp[64] = m; pp[65] = s; }
    }
    return;
  }

  int id = bid - 544;
  int wdw = id % NWIN;
  int rem = id / NWIN;
  int h = rem & 15, b = rem >> 4;

  u16* Ks = (u16*)smem;
  u16* Vt = Ks + 256 * 64;

  int lane = t & 63, wv = t >> 6;
  int g = lane >> 4, lr = lane & 15;
  size_t rowbase = (size_t)b * L_TOT + 1 + (size_t)wdw * 128;
  int hoff = h * 64;

  {
    int rsub = t >> 3;
    int ssrc = ((t & 7) ^ (rsub & 7)) * 8;
    const u16* kp = Kb + (rowbase + rsub) * E_DIM + hoff + ssrc;
#pragma unroll
    for (int c = 0; c < 8; c++)
      GLOAD16(kp + (size_t)c * 32 * E_DIM, Ks + c * 2048 + wv * 512);
  }
#pragma unroll
  for (int rep = 0; rep < 8; rep++) {
    int u = rep * 256 + t;
    int i = u >> 3;
    int d0 = (u & 7) * 8;
    uint4 v = *(const uint4*)(Vb + (rowbase + i) * E_DIM + hoff + d0);
    const u16* pv = (const u16*)&v;
#pragma unroll
    for (int j = 0; j < 8; j++) Vt[VT_IDX(d0 + j, i)] = pv[j];
  }
  __syncthreads();

  int slo = (2 * (g & 1)) * 16 + lr;
  int shi = slo + 16;

  for (int grp = 0; grp < 4; grp++) {
    int q0 = grp * 64 + wv * 16;
    const u16* qp = Qb + (rowbase + q0 + lr) * E_DIM + hoff;
    bf16x8 qa0 = *(const bf16x8*)(qp + g * 8);
    bf16x8 qa1 = *(const bf16x8*)(qp + 32 + g * 8);

    f4_t s[16];
    __builtin_amdgcn_s_setprio(1);
#pragma unroll
    for (int ki = 0; ki < 16; ki++) {
      int row = ki * 16 + lr;
      bf16x8 ka0 = *(const bf16x8*)&Ks[row * 64 + ((g ^ (lr & 7)) << 3)];
      bf16x8 ka1 = *(const bf16x8*)&Ks[row * 64 + (((4 + g) ^ (lr & 7)) << 3)];
      f4_t z = {};
      z = mfma16(ka0, qa0, z);
      z = mfma16(ka1, qa1, z);
      s[ki] = z;
    }
    __builtin_amdgcn_s_setprio(0);

    float mx = -1e30f;
#pragma unroll
    for (int ki = 0; ki < 16; ki++) {
      mx = fmaxf(mx, fmaxf(fmaxf(s[ki][0], s[ki][1]), fmaxf(s[ki][2], s[ki][3])));
    }
    mx = fmaxf(mx, __shfl_xor(mx, 16));
    mx = fmaxf(mx, __shfl_xor(mx, 32));
    float mx8 = mx * 0.125f;
    float sum = 0.f;
    u32 pk[16][2];
#pragma unroll
    for (int ki = 0; ki < 16; ki++) {
      float p0 = __expf(fmaf(s[ki][0], 0.125f, -mx8));
      float p1 = __expf(fmaf(s[ki][1], 0.125f, -mx8));
      float p2 = __expf(fmaf(s[ki][2], 0.125f, -mx8));
      float p3 = __expf(fmaf(s[ki][3], 0.125f, -mx8));
      sum += (p0 + p1) + (p2 + p3);
      pk[ki][0] = cvtpk(p0, p1);
      pk[ki][1] = cvtpk(p2, p3);
    }
    sum += __shfl_xor(sum, 16);
    sum += __shfl_xor(sum, 32);
    float inv = 1.0f / sum;

    u32 paw[8][4];
    bool hi = g >= 2;
#pragma unroll
    for (int kt = 0; kt < 8; kt++) {
      u32 v00 = __shfl((int)pk[kt * 2][0], slo);
      u32 v01 = __shfl((int)pk[kt * 2][1], slo);
      u32 v10 = __shfl((int)pk[kt * 2 + 1][0], slo);
      u32 v11 = __shfl((int)pk[kt * 2 + 1][1], slo);
      u32 w00 = __shfl((int)pk[kt * 2][0], shi);
      u32 w01 = __shfl((int)pk[kt * 2][1], shi);
      u32 w10 = __shfl((int)pk[kt * 2 + 1][0], shi);
      u32 w11 = __shfl((int)pk[kt * 2 + 1][1], shi);
      paw[kt][0] = hi ? v10 : v00;
      paw[kt][1] = hi ? v11 : v01;
      paw[kt][2] = hi ? w10 : w00;
      paw[kt][3] = hi ? w11 : w01;
    }

    f4_t o[4] = {};
    __builtin_amdgcn_s_setprio(1);
#pragma unroll
    for (int dtile = 0; dtile < 4; dtile++) {
      int d = dtile * 16 + lr;
      int dswz = (((d >> 3) & 7) << 3);
#pragma unroll
      for (int kt = 0; kt < 8; kt++) {
        int kphys = (kt * 32 + g * 8) ^ dswz;
        bf16x8 vb = *(const bf16x8*)&Vt[d * 264 + kphys];
        o[dtile] = mfma16(*(const bf16x8*)&paw[kt][0], vb, o[dtile]);
      }
    }
    __builtin_amdgcn_s_setprio(0);

    float invr[4];
#pragma unroll
    for (int r = 0; r < 4; r++) invr[r] = __shfl(inv, g * 4 + r);
    size_t orow = (size_t)(b * NWIN + wdw) * 256 + q0;
#pragma unroll
    for (int dtile = 0; dtile < 4; dtile++) {
#pragma unroll
      for (int r = 0; r < 4; r++) {
        winctx[(orow + g * 4 + r) * E_DIM + hoff + dtile * 16 + lr] =
            f2b(o[dtile][r] * invr[r]);
      }
    }
  }
}

// ------- combine2: overlap-average (blocks 0..4095) + gattn2 (block 4096) -------
__global__ __launch_bounds__(256) void combine2_kernel(const u16* __restrict__ winctx,
                                                       const float* __restrict__ part,
                                                       u16* __restrict__ ctxb) {
  if (blockIdx.x == 4096) {
    for (int i = threadIdx.x; i < 2048; i += 256) {
      int bh = i >> 6, d = i & 63;
      int b = bh >> 4, h = bh & 15;
      const float* pp = part + ((size_t)(b * HHEADS + h) * GCHUNKS) * 66;
      float m = -1e30f;
#pragma unroll
      for (int c = 0; c < GCHUNKS; c++) m = fmaxf(m, pp[c * 66 + 64]);
      float stot = 0.f, acc = 0.f;
#pragma unroll
      for (int c = 0; c < GCHUNKS; c++) {
        float w = __expf(pp[c * 66 + 64] - m);
        stot += pp[c * 66 + 65] * w;
        acc += pp[c * 66 + d] * w;
      }
      ctxb[(size_t)b * L_TOT * E_DIM + h * 64 + d] = f2b(acc / stot);
    }
    return;
  }
  int idx = blockIdx.x * 256 + threadIdx.x;
  int e0 = (idx & 127) * 8;
  int p = (idx >> 7) & 4095;
  int b = idx >> 19;
  int whi = p >> 7;
  if (whi > 30) whi = 30;
  int off_hi = p - whi * 128;
  int wlo = whi - 1;
  bool has_lo = (wlo >= 0) && (off_hi < 128);

  uint4 vhi = *(const uint4*)(winctx + (((size_t)(b * NWIN + whi) * 256 + off_hi) * E_DIM) + e0);
  const u16* ph = (const u16*)&vhi;
  float vals[8];
#pragma unroll
  for (int j = 0; j < 8; j++) vals[j] = b2f(ph[j]);
  if (has_lo) {
    uint4 vlo = *(const uint4*)(winctx + (((size_t)(b * NWIN + wlo) * 256 + off_hi + 128) * E_DIM) + e0);
    const u16* pl = (const u16*)&vlo;
#pragma unroll
    for (int j = 0; j < 8; j++) vals[j] = (vals[j] + b2f(pl[j])) * 0.5f;
  }
  u16 out[8];
#pragma unroll
  for (int j = 0; j < 8; j++) out[j] = f2b(vals[j]);
  *(uint4*)(ctxb + ((size_t)b * L_TOT + 1 + p) * E_DIM + e0) = *(uint4*)out;
}

// ---------------- launch ----------------
extern "C" void kernel_launch(void* const* d_in, const int* in_sizes, int n_in,
                              void* d_out, int out_size, void* d_ws, size_t ws_size,
                              hipStream_t stream) {
  const float* hs = (const float*)d_in[0];
  const float* Wq = (const float*)d_in[1];
  const float* bq = (const float*)d_in[2];
  const float* Wk = (const float*)d_in[3];
  const float* bk = (const float*)d_in[4];
  const float* Wv = (const float*)d_in[5];
  const float* bv = (const float*)d_in[6];
  const float* Wo = (const float*)d_in[7];
  const float* bo = (const float*)d_in[8];

  const size_t BLE = (size_t)M_ROWS * E_DIM;
  const size_t BLE_B = BLE * 2;
  const size_t EE = (size_t)E_DIM * E_DIM;

  char* ws = (char*)d_ws;
  u16* hsb = (u16*)(ws);
  u16* wtb = (u16*)(ws + BLE_B);
  u16* qkv = (u16*)(ws + BLE_B + 4 * EE * 2);
  u16* Qb = qkv;
  u16* Kb = qkv + BLE;
  u16* Vb = qkv + 2 * BLE;
  u16* ctxb = (u16*)(ws + BLE_B + 4 * EE * 2 + 3 * BLE_B);
  u16* winctx = (u16*)(ws + BLE_B + 4 * EE * 2 + 4 * BLE_B);
  float* gpart = (float*)(ws + BLE_B + 4 * EE * 2 + 4 * BLE_B +
                          (size_t)B_SZ * NWIN * 256 * E_DIM * 2);

  // fused hs convert + weight transpose
  prep_kernel<<<M_ROWS + 4096, 256, 0, stream>>>(hs, hsb, Wq, Wk, Wv, Wo, wtb);
  // QKV fused: 65 m-tiles x 12 n-tiles (BN=256) -> grid 784 (4 idle blocks)
  gemmF_qkv<<<784, 256, 0, stream>>>(hsb, wtb, bq, bk, bv, qkv, M_ROWS);
  // fused gattn1 (544) + wattn (992) = 1536 blocks
  attn_fused<<<1536, 256, 0, stream>>>(Qb, Kb, Vb, gpart, winctx);
  combine2_kernel<<<4097, 256, 0, stream>>>(winctx, gpart, ctxb);
  // output projection: 65 m-tiles x 8 n-tiles (BN=128) = 520 blocks
  gemmC_out<<<520, 256, 0, stream>>>(ctxb, wtb + 3 * EE, bo, d_out, M_ROWS);
}